// Round 16
// baseline (265.328 us; speedup 1.0000x reference)
//
#include <hip/hip_runtime.h>
#include <hip/hip_fp16.h>

// GCN 2-layer forward, CSR-gather with fixed-capacity radix binning.
// (R15 structure — 193.3 us — with 2-node-per-wave gathers.)
//   (memset) : zero bucket counters
//   k_binA   : scatter packed records (src<<8 | dstLocal); NT stores
//   k_binB   : per-bucket CSR build in LDS -> esrc (in-place), sc, dinv
//   k_xw     : xws = f16((x @ W1) * dinv)  [f32 W1 LDS, XOR-swizzled float4]
//   k_gather1 : 2 nodes/wave, half2, 8-way edge split, peeled round-0
//   k_gather2h: same over hsc; fused W2 epilogue (both nodes)
// d_out = [out (N*32) | h (N*16)]

#define NN 100000
#define NHALF 50000
#define NE 3200000
#define FIN 512
#define HID 16
#define NCLS 32
#define NB 391          // ceil(NN/256)
#define NBP 512         // padded bucket slots
#define CAP_B 9216      // fixed slots per bucket (mean 8184, +11 sigma)

// workspace element offsets (4-byte units)
#define OFF_BCNT  0                     // int [NBP]
#define OFF_SC    (NBP)                 // int2 [NN]  (start, cnt)
#define OFF_DINV  (NBP + 2*NN)          // float [NN]
#define OFF_EP    (NBP + 3*NN)          // u32 [NB*CAP_B]; becomes esrc
#define OFF_XWS   (OFF_EP + NB*CAP_B)   // half [NN*16] = NN*8 words
#define OFF_HSC   (OFF_XWS + NN*8)      // half [NN*16] = NN*8 words

// Bin edges into fixed-cap bucket regions. 512 thr/block, 8 edges/thread.
__global__ __launch_bounds__(512) void k_binA(const int* __restrict__ src,
                                              const int* __restrict__ dst,
                                              int* __restrict__ bcnt,
                                              unsigned* __restrict__ ep) {
    __shared__ int hist[NBP];
    __shared__ int gpos[NBP];
    int tid = threadIdx.x;
    hist[tid] = 0;
    __syncthreads();
    int base = blockIdx.x * 4096;
    unsigned rec[8];
    int meta[8];                        // (p_local << 9) | bucket, or -1
#pragma unroll
    for (int k = 0; k < 8; ++k) {
        int e = base + tid + k * 512;
        if (e < NE) {
            int s = __builtin_nontemporal_load(src + e);
            int d = __builtin_nontemporal_load(dst + e);
            int b = d >> 8;
            int p = atomicAdd(&hist[b], 1);
            rec[k] = ((unsigned)s << 8) | (unsigned)(d & 255);
            meta[k] = (p << 9) | b;
        } else meta[k] = -1;
    }
    __syncthreads();
    int v = hist[tid];
    if (v > 0) gpos[tid] = atomicAdd(&bcnt[tid], v);   // direct reservation
    __syncthreads();
#pragma unroll
    for (int k = 0; k < 8; ++k) {
        if (meta[k] >= 0) {
            int b = meta[k] & 511;
            int p = meta[k] >> 9;
            __builtin_nontemporal_store(rec[k], &ep[b * CAP_B + gpos[b] + p]);
        }
    }
}

// Per-bucket CSR build in LDS. Block b owns nodes [b*256, b*256+256).
__global__ __launch_bounds__(256) void k_binB(unsigned* __restrict__ ep,
                                              const int* __restrict__ bcnt,
                                              int2* __restrict__ sc,
                                              float* __restrict__ dinv) {
    __shared__ int nh[256];
    __shared__ int ns[256];
    __shared__ int np_[256];
    __shared__ int esL[CAP_B];
    int tid = threadIdx.x;
    int b = blockIdx.x;
    int gbase = b * CAP_B;
    int bc = bcnt[b];
    if (bc > CAP_B) bc = CAP_B;         // defensive clamp
    nh[tid] = 0;
    __syncthreads();
    for (int t = tid; t < bc; t += 256)
        atomicAdd(&nh[ep[gbase + t] & 255], 1);
    __syncthreads();
    int v = nh[tid];
    ns[tid] = v;
    __syncthreads();
#pragma unroll
    for (int o = 1; o < 256; o <<= 1) {
        int u = (tid >= o) ? ns[tid - o] : 0;
        __syncthreads();
        ns[tid] += u;
        __syncthreads();
    }
    int ex = ns[tid] - v;               // exclusive start within bucket
    np_[tid] = ex;
    __syncthreads();
    for (int t = tid; t < bc; t += 256) {
        unsigned r = ep[gbase + t];
        int dl = r & 255;
        int p = atomicAdd(&np_[dl], 1);
        esL[p] = (int)(r >> 8);
    }
    __syncthreads();
    for (int t = tid; t < bc; t += 256)
        ep[gbase + t] = (unsigned)esL[t];   // in-place: ep becomes esrc
    int node = b * 256 + tid;
    if (node < NN) {
        sc[node] = make_int2(gbase + ex, v);
        dinv[node] = rsqrtf((float)(v + 1));
    }
}

// GEMM1: 4-way k-split, 2 nodes per thread; XOR-swizzled f32 W1 in LDS;
// f16 output. (R7-proven structure.)
__global__ __launch_bounds__(256) void k_xw(const float* __restrict__ x,
                                            const float* __restrict__ W1,
                                            const float* __restrict__ dinv,
                                            __half* __restrict__ xws) {
    __shared__ float w1[FIN * HID];     // 32 KB, XOR-swizzled float4 blocks
    for (int t = threadIdx.x; t < FIN * HID; t += 256) {
        int k = t >> 4, j = t & 15;
        int s = (k * 4 + ((j >> 2) ^ ((k >> 2) & 3))) * 4 + (j & 3);
        w1[s] = W1[t];
    }
    __syncthreads();
    int w  = threadIdx.x >> 6;          // wave in block (0..3)
    int nl = (threadIdx.x >> 2) & 15;   // node slot
    int c  = threadIdx.x & 3;           // k-split group
    int n0 = blockIdx.x * 128 + w * 32 + nl;
    int n1 = n0 + 16;
    bool v0 = n0 < NN, v1 = n1 < NN;
    const float4* x4 = reinterpret_cast<const float4*>(x);
    const float4* r0 = x4 + (v0 ? (size_t)n0 * (FIN / 4) : 0);
    const float4* r1 = x4 + (v1 ? (size_t)n1 * (FIN / 4) : 0);
    const float4* wv = reinterpret_cast<const float4*>(w1);
    float a0[HID], a1[HID];
#pragma unroll
    for (int j = 0; j < HID; ++j) { a0[j] = 0.f; a1[j] = 0.f; }
#pragma unroll 4
    for (int t = 0; t < 32; ++t) {
        int qk = c + 4 * t;             // float4-quad index into the row
        float4 xv0 = r0[qk];
        float4 xv1 = r1[qk];
        const float4* wb = wv + qk * 16;
#pragma unroll
        for (int e = 0; e < 4; ++e) {
            float xe0 = (e == 0) ? xv0.x : (e == 1) ? xv0.y : (e == 2) ? xv0.z : xv0.w;
            float xe1 = (e == 0) ? xv1.x : (e == 1) ? xv1.y : (e == 2) ? xv1.z : xv1.w;
#pragma unroll
            for (int j4 = 0; j4 < 4; ++j4) {
                float4 w4 = wb[e * 4 + (j4 ^ c)];   // true w1[k][j4*4..+3]
                a0[j4 * 4 + 0] += xe0 * w4.x;
                a0[j4 * 4 + 1] += xe0 * w4.y;
                a0[j4 * 4 + 2] += xe0 * w4.z;
                a0[j4 * 4 + 3] += xe0 * w4.w;
                a1[j4 * 4 + 0] += xe1 * w4.x;
                a1[j4 * 4 + 1] += xe1 * w4.y;
                a1[j4 * 4 + 2] += xe1 * w4.z;
                a1[j4 * 4 + 3] += xe1 * w4.w;
            }
        }
    }
#pragma unroll
    for (int j = 0; j < HID; ++j) {
        a0[j] += __shfl_xor(a0[j], 1);
        a0[j] += __shfl_xor(a0[j], 2);
        a1[j] += __shfl_xor(a1[j], 1);
        a1[j] += __shfl_xor(a1[j], 2);
    }
    if (c == 0) {
        if (v0) {
            float dv = dinv[n0];
            __half2 hv[8];
#pragma unroll
            for (int k = 0; k < 8; ++k)
                hv[k] = __floats2half2_rn(a0[2 * k] * dv, a0[2 * k + 1] * dv);
            float4* o = reinterpret_cast<float4*>(xws + (size_t)n0 * HID);
            o[0] = *reinterpret_cast<float4*>(&hv[0]);
            o[1] = *reinterpret_cast<float4*>(&hv[4]);
        }
        if (v1) {
            float dv = dinv[n1];
            __half2 hv[8];
#pragma unroll
            for (int k = 0; k < 8; ++k)
                hv[k] = __floats2half2_rn(a1[2 * k] * dv, a1[2 * k + 1] * dv);
            float4* o = reinterpret_cast<float4*>(xws + (size_t)n1 * HID);
            o[0] = *reinterpret_cast<float4*>(&hv[0]);
            o[1] = *reinterpret_cast<float4*>(&hv[4]);
        }
    }
}

// Gather layer 1: 2 nodes per wave (i, i+NHALF). j2 = lane&7, c = lane>>3.
// Peeled round-0 issues both nodes' sc/idx/gather chains in parallel.
__global__ __launch_bounds__(256) void k_gather1(const int2* __restrict__ sc,
                                                 const int* __restrict__ esrc,
                                                 const __half2* __restrict__ xws2,
                                                 const float* __restrict__ dinv,
                                                 const float* __restrict__ b1,
                                                 float* __restrict__ hout,
                                                 __half2* __restrict__ hsc2) {
    int wv = (blockIdx.x * 256 + threadIdx.x) >> 6;
    if (wv >= NHALF) return;
    int i0 = wv, i1 = wv + NHALF;
    int lane = threadIdx.x & 63;
    int j2 = lane & 7;
    int c = lane >> 3;                  // 0..7
    int2 A = sc[i0], B = sc[i1];
    int stA = A.x + c, enA = A.x + A.y;
    int stB = B.x + c, enB = B.x + B.y;
    float sxA[8], syA[8], sxB[8], syB[8];
#pragma unroll
    for (int k = 0; k < 8; ++k) { sxA[k] = 0.f; syA[k] = 0.f; sxB[k] = 0.f; syB[k] = 0.f; }
    // round 0: both nodes, 64 edges each in flight
    {
        int aA[8], aB[8];
#pragma unroll
        for (int k = 0; k < 8; ++k) {
            int eA = stA + 8 * k;
            int eB = stB + 8 * k;
            aA[k] = __builtin_nontemporal_load(esrc + (eA < enA ? eA : A.x));
            aB[k] = __builtin_nontemporal_load(esrc + (eB < enB ? eB : B.x));
        }
#pragma unroll
        for (int k = 0; k < 8; ++k) {
            bool okA = (stA + 8 * k) < enA;
            bool okB = (stB + 8 * k) < enB;
            float2 fA = __half22float2(xws2[(okA ? aA[k] : 0) * 8 + j2]);
            float2 fB = __half22float2(xws2[(okB ? aB[k] : 0) * 8 + j2]);
            sxA[k] += okA ? fA.x : 0.f;  syA[k] += okA ? fA.y : 0.f;
            sxB[k] += okB ? fB.x : 0.f;  syB[k] += okB ? fB.y : 0.f;
        }
    }
    // remainders (rare: deg > 64)
    for (int e = stA + 64; e < enA; e += 64) {
        int a[8];
#pragma unroll
        for (int k = 0; k < 8; ++k) {
            int ee = e + 8 * k;
            a[k] = __builtin_nontemporal_load(esrc + (ee < enA ? ee : e));
        }
#pragma unroll
        for (int k = 0; k < 8; ++k) {
            float2 f = __half22float2(xws2[a[k] * 8 + j2]);
            bool ok = (e + 8 * k) < enA;
            sxA[k] += ok ? f.x : 0.f;
            syA[k] += ok ? f.y : 0.f;
        }
    }
    for (int e = stB + 64; e < enB; e += 64) {
        int a[8];
#pragma unroll
        for (int k = 0; k < 8; ++k) {
            int ee = e + 8 * k;
            a[k] = __builtin_nontemporal_load(esrc + (ee < enB ? ee : e));
        }
#pragma unroll
        for (int k = 0; k < 8; ++k) {
            float2 f = __half22float2(hsc2 == nullptr ? make_half2(__float2half(0.f), __float2half(0.f)) : xws2[a[k] * 8 + j2]);
            bool ok = (e + 8 * k) < enB;
            sxB[k] += ok ? f.x : 0.f;
            syB[k] += ok ? f.y : 0.f;
        }
    }
    float sumxA = ((sxA[0] + sxA[1]) + (sxA[2] + sxA[3])) + ((sxA[4] + sxA[5]) + (sxA[6] + sxA[7]));
    float sumyA = ((syA[0] + syA[1]) + (syA[2] + syA[3])) + ((syA[4] + syA[5]) + (syA[6] + syA[7]));
    float sumxB = ((sxB[0] + sxB[1]) + (sxB[2] + sxB[3])) + ((sxB[4] + sxB[5]) + (sxB[6] + sxB[7]));
    float sumyB = ((syB[0] + syB[1]) + (syB[2] + syB[3])) + ((syB[4] + syB[5]) + (syB[6] + syB[7]));
    sumxA += __shfl_xor(sumxA, 8);  sumyA += __shfl_xor(sumyA, 8);
    sumxA += __shfl_xor(sumxA, 16); sumyA += __shfl_xor(sumyA, 16);
    sumxA += __shfl_xor(sumxA, 32); sumyA += __shfl_xor(sumyA, 32);
    sumxB += __shfl_xor(sumxB, 8);  sumyB += __shfl_xor(sumyB, 8);
    sumxB += __shfl_xor(sumxB, 16); sumyB += __shfl_xor(sumyB, 16);
    sumxB += __shfl_xor(sumxB, 32); sumyB += __shfl_xor(sumyB, 32);
    if (c == 0) {
        float dvA = dinv[i0], dvB = dinv[i1];
        float2 selfA = __half22float2(xws2[i0 * 8 + j2]);
        float2 selfB = __half22float2(xws2[i1 * 8 + j2]);
        float vxA = b1[2 * j2]     + dvA * (sumxA + selfA.x);
        float vyA = b1[2 * j2 + 1] + dvA * (sumyA + selfA.y);
        float vxB = b1[2 * j2]     + dvB * (sumxB + selfB.x);
        float vyB = b1[2 * j2 + 1] + dvB * (sumyB + selfB.y);
        float hxA = vxA > 0.f ? vxA : 0.f, hyA = vyA > 0.f ? vyA : 0.f;
        float hxB = vxB > 0.f ? vxB : 0.f, hyB = vyB > 0.f ? vyB : 0.f;
        *reinterpret_cast<float2*>(hout + i0 * HID + 2 * j2) = make_float2(hxA, hyA);
        *reinterpret_cast<float2*>(hout + i1 * HID + 2 * j2) = make_float2(hxB, hyB);
        hsc2[i0 * 8 + j2] = __floats2half2_rn(hxA * dvA, hyA * dvA);
        hsc2[i1 * 8 + j2] = __floats2half2_rn(hxB * dvB, hyB * dvB);
    }
}

// Gather layer 2 with fused W2: 2 nodes per wave over hsc.
__global__ __launch_bounds__(256) void k_gather2h(const int2* __restrict__ sc,
                                                  const int* __restrict__ esrc,
                                                  const __half2* __restrict__ hsc2,
                                                  const float* __restrict__ dinv,
                                                  const float* __restrict__ W2,
                                                  const float* __restrict__ b2,
                                                  float* __restrict__ out) {
    __shared__ float w2s[HID * NCLS];
    __shared__ float b2s[NCLS];
    for (int t = threadIdx.x; t < HID * NCLS; t += 256) w2s[t] = W2[t];
    if (threadIdx.x < NCLS) b2s[threadIdx.x] = b2[threadIdx.x];
    __syncthreads();
    int wv = (blockIdx.x * 256 + threadIdx.x) >> 6;
    if (wv >= NHALF) return;
    int i0 = wv, i1 = wv + NHALF;
    int lane = threadIdx.x & 63;
    int j2 = lane & 7;
    int c = lane >> 3;                  // 0..7
    int2 A = sc[i0], B = sc[i1];
    int stA = A.x + c, enA = A.x + A.y;
    int stB = B.x + c, enB = B.x + B.y;
    float sxA[8], syA[8], sxB[8], syB[8];
#pragma unroll
    for (int k = 0; k < 8; ++k) { sxA[k] = 0.f; syA[k] = 0.f; sxB[k] = 0.f; syB[k] = 0.f; }
    {
        int aA[8], aB[8];
#pragma unroll
        for (int k = 0; k < 8; ++k) {
            int eA = stA + 8 * k;
            int eB = stB + 8 * k;
            aA[k] = __builtin_nontemporal_load(esrc + (eA < enA ? eA : A.x));
            aB[k] = __builtin_nontemporal_load(esrc + (eB < enB ? eB : B.x));
        }
#pragma unroll
        for (int k = 0; k < 8; ++k) {
            bool okA = (stA + 8 * k) < enA;
            bool okB = (stB + 8 * k) < enB;
            float2 fA = __half22float2(hsc2[(okA ? aA[k] : 0) * 8 + j2]);
            float2 fB = __half22float2(hsc2[(okB ? aB[k] : 0) * 8 + j2]);
            sxA[k] += okA ? fA.x : 0.f;  syA[k] += okA ? fA.y : 0.f;
            sxB[k] += okB ? fB.x : 0.f;  syB[k] += okB ? fB.y : 0.f;
        }
    }
    for (int e = stA + 64; e < enA; e += 64) {
        int a[8];
#pragma unroll
        for (int k = 0; k < 8; ++k) {
            int ee = e + 8 * k;
            a[k] = __builtin_nontemporal_load(esrc + (ee < enA ? ee : e));
        }
#pragma unroll
        for (int k = 0; k < 8; ++k) {
            float2 f = __half22float2(hsc2[a[k] * 8 + j2]);
            bool ok = (e + 8 * k) < enA;
            sxA[k] += ok ? f.x : 0.f;
            syA[k] += ok ? f.y : 0.f;
        }
    }
    for (int e = stB + 64; e < enB; e += 64) {
        int a[8];
#pragma unroll
        for (int k = 0; k < 8; ++k) {
            int ee = e + 8 * k;
            a[k] = __builtin_nontemporal_load(esrc + (ee < enB ? ee : e));
        }
#pragma unroll
        for (int k = 0; k < 8; ++k) {
            float2 f = __half22float2(hsc2[a[k] * 8 + j2]);
            bool ok = (e + 8 * k) < enB;
            sxB[k] += ok ? f.x : 0.f;
            syB[k] += ok ? f.y : 0.f;
        }
    }
    float sumxA = ((sxA[0] + sxA[1]) + (sxA[2] + sxA[3])) + ((sxA[4] + sxA[5]) + (sxA[6] + sxA[7]));
    float sumyA = ((syA[0] + syA[1]) + (syA[2] + syA[3])) + ((syA[4] + syA[5]) + (syA[6] + syA[7]));
    float sumxB = ((sxB[0] + sxB[1]) + (sxB[2] + sxB[3])) + ((sxB[4] + sxB[5]) + (sxB[6] + sxB[7]));
    float sumyB = ((syB[0] + syB[1]) + (syB[2] + syB[3])) + ((syB[4] + syB[5]) + (syB[6] + syB[7]));
    sumxA += __shfl_xor(sumxA, 8);  sumyA += __shfl_xor(sumyA, 8);
    sumxA += __shfl_xor(sumxA, 16); sumyA += __shfl_xor(sumyA, 16);
    sumxA += __shfl_xor(sumxA, 32); sumyA += __shfl_xor(sumyA, 32);
    sumxB += __shfl_xor(sumxB, 8);  sumyB += __shfl_xor(sumyB, 8);
    sumxB += __shfl_xor(sumxB, 16); sumyB += __shfl_xor(sumyB, 16);
    sumxB += __shfl_xor(sumxB, 32); sumyB += __shfl_xor(sumyB, 32);
    {   // self-loop terms
        float2 sA = __half22float2(hsc2[i0 * 8 + j2]);
        float2 sB = __half22float2(hsc2[i1 * 8 + j2]);
        sumxA += sA.x;  sumyA += sA.y;
        sumxB += sB.x;  sumyB += sB.y;
    }
    int jo = lane & 31;
    float accA = 0.f, accB = 0.f;
#pragma unroll
    for (int p = 0; p < 8; ++p) {
        float wx = w2s[(2 * p) * NCLS + jo];
        float wy = w2s[(2 * p + 1) * NCLS + jo];
        accA += __shfl(sumxA, p) * wx + __shfl(sumyA, p) * wy;
        accB += __shfl(sumxB, p) * wx + __shfl(sumyB, p) * wy;
    }
    if (lane < 32) {
        out[i0 * NCLS + jo] = b2s[jo] + dinv[i0] * accA;
        out[i1 * NCLS + jo] = b2s[jo] + dinv[i1] * accB;
    }
}

extern "C" void kernel_launch(void* const* d_in, const int* in_sizes, int n_in,
                              void* d_out, int out_size, void* d_ws, size_t ws_size,
                              hipStream_t stream) {
    const float* x  = (const float*)d_in[0];
    const int* ei   = (const int*)d_in[1];      // [2][NE]
    const float* W1 = (const float*)d_in[2];
    const float* b1 = (const float*)d_in[3];
    const float* W2 = (const float*)d_in[4];
    const float* b2 = (const float*)d_in[5];

    const int* src = ei;
    const int* dst = ei + NE;

    int* wsi = (int*)d_ws;
    int*      bcnt  = wsi + OFF_BCNT;
    int2*     sc    = (int2*)(wsi + OFF_SC);
    float*    dinv  = (float*)(wsi + OFF_DINV);
    unsigned* ep    = (unsigned*)(wsi + OFF_EP);   // packed, then esrc
    __half*   xws   = (__half*)(wsi + OFF_XWS);
    __half2*  xws2  = (__half2*)(wsi + OFF_XWS);
    __half2*  hsc2  = (__half2*)(wsi + OFF_HSC);

    float* outp = (float*)d_out;           // [NN*32]
    float* hout = outp + NN * NCLS;        // [NN*16]

    const int B = 256;

    hipMemsetAsync(bcnt, 0, NBP * sizeof(int), stream);
    hipLaunchKernelGGL(k_binA,  dim3((NE + 4095) / 4096), dim3(512), 0, stream, src, dst, bcnt, ep);
    hipLaunchKernelGGL(k_binB,  dim3(NB), dim3(B), 0, stream, ep, bcnt, sc, dinv);
    hipLaunchKernelGGL(k_xw,    dim3((NN + 127) / 128), dim3(B), 0, stream, x, W1, dinv, xws);
    hipLaunchKernelGGL(k_gather1, dim3((NHALF * 64 + B - 1) / B), dim3(B), 0, stream,
                       sc, (const int*)ep, xws2, dinv, b1, hout, hsc2);
    hipLaunchKernelGGL(k_gather2h, dim3((NHALF * 64 + B - 1) / B), dim3(B), 0, stream,
                       sc, (const int*)ep, hsc2, dinv, W2, b2, outp);
}

// Round 17
// 179.777 us; speedup vs baseline: 1.4759x; 1.4759x over previous
//
#include <hip/hip_runtime.h>
#include <hip/hip_fp16.h>

// GCN 2-layer forward, CSR-gather with fixed-capacity radix binning.
// (R15 base + 2-node-per-wave gathers; NT store on binA REVERTED — it caused
//  write-through amplification, 12.5 MB -> 132 MB HBM writes, +70 us.)
//   (memset) : zero bucket counters
//   k_binA   : scatter packed records (src<<8 | dstLocal); plain stores
//   k_binB   : per-bucket CSR build in LDS -> esrc (in-place), sc, dinv
//   k_xw     : xws = f16((x @ W1) * dinv)  [f32 W1 LDS, XOR-swizzled float4]
//   k_gather1 : 2 nodes/wave, half2, 8-way edge split, peeled round-0
//   k_gather2h: same over hsc; fused W2 epilogue (both nodes)
// d_out = [out (N*32) | h (N*16)]

#define NN 100000
#define NHALF 50000
#define NE 3200000
#define FIN 512
#define HID 16
#define NCLS 32
#define NB 391          // ceil(NN/256)
#define NBP 512         // padded bucket slots
#define CAP_B 9216      // fixed slots per bucket (mean 8184, +11 sigma)

// workspace element offsets (4-byte units)
#define OFF_BCNT  0                     // int [NBP]
#define OFF_SC    (NBP)                 // int2 [NN]  (start, cnt)
#define OFF_DINV  (NBP + 2*NN)          // float [NN]
#define OFF_EP    (NBP + 3*NN)          // u32 [NB*CAP_B]; becomes esrc
#define OFF_XWS   (OFF_EP + NB*CAP_B)   // half [NN*16] = NN*8 words
#define OFF_HSC   (OFF_XWS + NN*8)      // half [NN*16] = NN*8 words

// Bin edges into fixed-cap bucket regions. 512 thr/block, 8 edges/thread.
__global__ __launch_bounds__(512) void k_binA(const int* __restrict__ src,
                                              const int* __restrict__ dst,
                                              int* __restrict__ bcnt,
                                              unsigned* __restrict__ ep) {
    __shared__ int hist[NBP];
    __shared__ int gpos[NBP];
    int tid = threadIdx.x;
    hist[tid] = 0;
    __syncthreads();
    int base = blockIdx.x * 4096;
    unsigned rec[8];
    int meta[8];                        // (p_local << 9) | bucket, or -1
#pragma unroll
    for (int k = 0; k < 8; ++k) {
        int e = base + tid + k * 512;
        if (e < NE) {
            int s = __builtin_nontemporal_load(src + e);
            int d = __builtin_nontemporal_load(dst + e);
            int b = d >> 8;
            int p = atomicAdd(&hist[b], 1);
            rec[k] = ((unsigned)s << 8) | (unsigned)(d & 255);
            meta[k] = (p << 9) | b;
        } else meta[k] = -1;
    }
    __syncthreads();
    int v = hist[tid];
    if (v > 0) gpos[tid] = atomicAdd(&bcnt[tid], v);   // direct reservation
    __syncthreads();
#pragma unroll
    for (int k = 0; k < 8; ++k) {
        if (meta[k] >= 0) {
            int b = meta[k] & 511;
            int p = meta[k] >> 9;
            ep[b * CAP_B + gpos[b] + p] = rec[k];   // plain store: L2 absorbs
        }
    }
}

// Per-bucket CSR build in LDS. Block b owns nodes [b*256, b*256+256).
__global__ __launch_bounds__(256) void k_binB(unsigned* __restrict__ ep,
                                              const int* __restrict__ bcnt,
                                              int2* __restrict__ sc,
                                              float* __restrict__ dinv) {
    __shared__ int nh[256];
    __shared__ int ns[256];
    __shared__ int np_[256];
    __shared__ int esL[CAP_B];
    int tid = threadIdx.x;
    int b = blockIdx.x;
    int gbase = b * CAP_B;
    int bc = bcnt[b];
    if (bc > CAP_B) bc = CAP_B;         // defensive clamp
    nh[tid] = 0;
    __syncthreads();
    for (int t = tid; t < bc; t += 256)
        atomicAdd(&nh[ep[gbase + t] & 255], 1);
    __syncthreads();
    int v = nh[tid];
    ns[tid] = v;
    __syncthreads();
#pragma unroll
    for (int o = 1; o < 256; o <<= 1) {
        int u = (tid >= o) ? ns[tid - o] : 0;
        __syncthreads();
        ns[tid] += u;
        __syncthreads();
    }
    int ex = ns[tid] - v;               // exclusive start within bucket
    np_[tid] = ex;
    __syncthreads();
    for (int t = tid; t < bc; t += 256) {
        unsigned r = ep[gbase + t];
        int dl = r & 255;
        int p = atomicAdd(&np_[dl], 1);
        esL[p] = (int)(r >> 8);
    }
    __syncthreads();
    for (int t = tid; t < bc; t += 256)
        ep[gbase + t] = (unsigned)esL[t];   // in-place: ep becomes esrc
    int node = b * 256 + tid;
    if (node < NN) {
        sc[node] = make_int2(gbase + ex, v);
        dinv[node] = rsqrtf((float)(v + 1));
    }
}

// GEMM1: 4-way k-split, 2 nodes per thread; XOR-swizzled f32 W1 in LDS;
// f16 output. (R7-proven structure.)
__global__ __launch_bounds__(256) void k_xw(const float* __restrict__ x,
                                            const float* __restrict__ W1,
                                            const float* __restrict__ dinv,
                                            __half* __restrict__ xws) {
    __shared__ float w1[FIN * HID];     // 32 KB, XOR-swizzled float4 blocks
    for (int t = threadIdx.x; t < FIN * HID; t += 256) {
        int k = t >> 4, j = t & 15;
        int s = (k * 4 + ((j >> 2) ^ ((k >> 2) & 3))) * 4 + (j & 3);
        w1[s] = W1[t];
    }
    __syncthreads();
    int w  = threadIdx.x >> 6;          // wave in block (0..3)
    int nl = (threadIdx.x >> 2) & 15;   // node slot
    int c  = threadIdx.x & 3;           // k-split group
    int n0 = blockIdx.x * 128 + w * 32 + nl;
    int n1 = n0 + 16;
    bool v0 = n0 < NN, v1 = n1 < NN;
    const float4* x4 = reinterpret_cast<const float4*>(x);
    const float4* r0 = x4 + (v0 ? (size_t)n0 * (FIN / 4) : 0);
    const float4* r1 = x4 + (v1 ? (size_t)n1 * (FIN / 4) : 0);
    const float4* wv = reinterpret_cast<const float4*>(w1);
    float a0[HID], a1[HID];
#pragma unroll
    for (int j = 0; j < HID; ++j) { a0[j] = 0.f; a1[j] = 0.f; }
#pragma unroll 4
    for (int t = 0; t < 32; ++t) {
        int qk = c + 4 * t;             // float4-quad index into the row
        float4 xv0 = r0[qk];
        float4 xv1 = r1[qk];
        const float4* wb = wv + qk * 16;
#pragma unroll
        for (int e = 0; e < 4; ++e) {
            float xe0 = (e == 0) ? xv0.x : (e == 1) ? xv0.y : (e == 2) ? xv0.z : xv0.w;
            float xe1 = (e == 0) ? xv1.x : (e == 1) ? xv1.y : (e == 2) ? xv1.z : xv1.w;
#pragma unroll
            for (int j4 = 0; j4 < 4; ++j4) {
                float4 w4 = wb[e * 4 + (j4 ^ c)];   // true w1[k][j4*4..+3]
                a0[j4 * 4 + 0] += xe0 * w4.x;
                a0[j4 * 4 + 1] += xe0 * w4.y;
                a0[j4 * 4 + 2] += xe0 * w4.z;
                a0[j4 * 4 + 3] += xe0 * w4.w;
                a1[j4 * 4 + 0] += xe1 * w4.x;
                a1[j4 * 4 + 1] += xe1 * w4.y;
                a1[j4 * 4 + 2] += xe1 * w4.z;
                a1[j4 * 4 + 3] += xe1 * w4.w;
            }
        }
    }
#pragma unroll
    for (int j = 0; j < HID; ++j) {
        a0[j] += __shfl_xor(a0[j], 1);
        a0[j] += __shfl_xor(a0[j], 2);
        a1[j] += __shfl_xor(a1[j], 1);
        a1[j] += __shfl_xor(a1[j], 2);
    }
    if (c == 0) {
        if (v0) {
            float dv = dinv[n0];
            __half2 hv[8];
#pragma unroll
            for (int k = 0; k < 8; ++k)
                hv[k] = __floats2half2_rn(a0[2 * k] * dv, a0[2 * k + 1] * dv);
            float4* o = reinterpret_cast<float4*>(xws + (size_t)n0 * HID);
            o[0] = *reinterpret_cast<float4*>(&hv[0]);
            o[1] = *reinterpret_cast<float4*>(&hv[4]);
        }
        if (v1) {
            float dv = dinv[n1];
            __half2 hv[8];
#pragma unroll
            for (int k = 0; k < 8; ++k)
                hv[k] = __floats2half2_rn(a1[2 * k] * dv, a1[2 * k + 1] * dv);
            float4* o = reinterpret_cast<float4*>(xws + (size_t)n1 * HID);
            o[0] = *reinterpret_cast<float4*>(&hv[0]);
            o[1] = *reinterpret_cast<float4*>(&hv[4]);
        }
    }
}

// Gather layer 1: 2 nodes per wave (i, i+NHALF). j2 = lane&7, c = lane>>3.
// Peeled round-0 issues both nodes' sc/idx/gather chains in parallel.
__global__ __launch_bounds__(256) void k_gather1(const int2* __restrict__ sc,
                                                 const int* __restrict__ esrc,
                                                 const __half2* __restrict__ xws2,
                                                 const float* __restrict__ dinv,
                                                 const float* __restrict__ b1,
                                                 float* __restrict__ hout,
                                                 __half2* __restrict__ hsc2) {
    int wv = (blockIdx.x * 256 + threadIdx.x) >> 6;
    if (wv >= NHALF) return;
    int i0 = wv, i1 = wv + NHALF;
    int lane = threadIdx.x & 63;
    int j2 = lane & 7;
    int c = lane >> 3;                  // 0..7
    int2 A = sc[i0], B = sc[i1];
    int stA = A.x + c, enA = A.x + A.y;
    int stB = B.x + c, enB = B.x + B.y;
    float sxA[8], syA[8], sxB[8], syB[8];
#pragma unroll
    for (int k = 0; k < 8; ++k) { sxA[k] = 0.f; syA[k] = 0.f; sxB[k] = 0.f; syB[k] = 0.f; }
    // round 0: both nodes, 64 edges each in flight
    {
        int aA[8], aB[8];
#pragma unroll
        for (int k = 0; k < 8; ++k) {
            int eA = stA + 8 * k;
            int eB = stB + 8 * k;
            aA[k] = __builtin_nontemporal_load(esrc + (eA < enA ? eA : A.x));
            aB[k] = __builtin_nontemporal_load(esrc + (eB < enB ? eB : B.x));
        }
#pragma unroll
        for (int k = 0; k < 8; ++k) {
            bool okA = (stA + 8 * k) < enA;
            bool okB = (stB + 8 * k) < enB;
            float2 fA = __half22float2(xws2[(okA ? aA[k] : 0) * 8 + j2]);
            float2 fB = __half22float2(xws2[(okB ? aB[k] : 0) * 8 + j2]);
            sxA[k] += okA ? fA.x : 0.f;  syA[k] += okA ? fA.y : 0.f;
            sxB[k] += okB ? fB.x : 0.f;  syB[k] += okB ? fB.y : 0.f;
        }
    }
    // remainders (rare: deg > 64)
    for (int e = stA + 64; e < enA; e += 64) {
        int a[8];
#pragma unroll
        for (int k = 0; k < 8; ++k) {
            int ee = e + 8 * k;
            a[k] = __builtin_nontemporal_load(esrc + (ee < enA ? ee : e));
        }
#pragma unroll
        for (int k = 0; k < 8; ++k) {
            float2 f = __half22float2(xws2[a[k] * 8 + j2]);
            bool ok = (e + 8 * k) < enA;
            sxA[k] += ok ? f.x : 0.f;
            syA[k] += ok ? f.y : 0.f;
        }
    }
    for (int e = stB + 64; e < enB; e += 64) {
        int a[8];
#pragma unroll
        for (int k = 0; k < 8; ++k) {
            int ee = e + 8 * k;
            a[k] = __builtin_nontemporal_load(esrc + (ee < enB ? ee : e));
        }
#pragma unroll
        for (int k = 0; k < 8; ++k) {
            float2 f = __half22float2(xws2[a[k] * 8 + j2]);
            bool ok = (e + 8 * k) < enB;
            sxB[k] += ok ? f.x : 0.f;
            syB[k] += ok ? f.y : 0.f;
        }
    }
    float sumxA = ((sxA[0] + sxA[1]) + (sxA[2] + sxA[3])) + ((sxA[4] + sxA[5]) + (sxA[6] + sxA[7]));
    float sumyA = ((syA[0] + syA[1]) + (syA[2] + syA[3])) + ((syA[4] + syA[5]) + (syA[6] + syA[7]));
    float sumxB = ((sxB[0] + sxB[1]) + (sxB[2] + sxB[3])) + ((sxB[4] + sxB[5]) + (sxB[6] + sxB[7]));
    float sumyB = ((syB[0] + syB[1]) + (syB[2] + syB[3])) + ((syB[4] + syB[5]) + (syB[6] + syB[7]));
    sumxA += __shfl_xor(sumxA, 8);  sumyA += __shfl_xor(sumyA, 8);
    sumxA += __shfl_xor(sumxA, 16); sumyA += __shfl_xor(sumyA, 16);
    sumxA += __shfl_xor(sumxA, 32); sumyA += __shfl_xor(sumyA, 32);
    sumxB += __shfl_xor(sumxB, 8);  sumyB += __shfl_xor(sumyB, 8);
    sumxB += __shfl_xor(sumxB, 16); sumyB += __shfl_xor(sumyB, 16);
    sumxB += __shfl_xor(sumxB, 32); sumyB += __shfl_xor(sumyB, 32);
    if (c == 0) {
        float dvA = dinv[i0], dvB = dinv[i1];
        float2 selfA = __half22float2(xws2[i0 * 8 + j2]);
        float2 selfB = __half22float2(xws2[i1 * 8 + j2]);
        float vxA = b1[2 * j2]     + dvA * (sumxA + selfA.x);
        float vyA = b1[2 * j2 + 1] + dvA * (sumyA + selfA.y);
        float vxB = b1[2 * j2]     + dvB * (sumxB + selfB.x);
        float vyB = b1[2 * j2 + 1] + dvB * (sumyB + selfB.y);
        float hxA = vxA > 0.f ? vxA : 0.f, hyA = vyA > 0.f ? vyA : 0.f;
        float hxB = vxB > 0.f ? vxB : 0.f, hyB = vyB > 0.f ? vyB : 0.f;
        *reinterpret_cast<float2*>(hout + i0 * HID + 2 * j2) = make_float2(hxA, hyA);
        *reinterpret_cast<float2*>(hout + i1 * HID + 2 * j2) = make_float2(hxB, hyB);
        hsc2[i0 * 8 + j2] = __floats2half2_rn(hxA * dvA, hyA * dvA);
        hsc2[i1 * 8 + j2] = __floats2half2_rn(hxB * dvB, hyB * dvB);
    }
}

// Gather layer 2 with fused W2: 2 nodes per wave over hsc.
__global__ __launch_bounds__(256) void k_gather2h(const int2* __restrict__ sc,
                                                  const int* __restrict__ esrc,
                                                  const __half2* __restrict__ hsc2,
                                                  const float* __restrict__ dinv,
                                                  const float* __restrict__ W2,
                                                  const float* __restrict__ b2,
                                                  float* __restrict__ out) {
    __shared__ float w2s[HID * NCLS];
    __shared__ float b2s[NCLS];
    for (int t = threadIdx.x; t < HID * NCLS; t += 256) w2s[t] = W2[t];
    if (threadIdx.x < NCLS) b2s[threadIdx.x] = b2[threadIdx.x];
    __syncthreads();
    int wv = (blockIdx.x * 256 + threadIdx.x) >> 6;
    if (wv >= NHALF) return;
    int i0 = wv, i1 = wv + NHALF;
    int lane = threadIdx.x & 63;
    int j2 = lane & 7;
    int c = lane >> 3;                  // 0..7
    int2 A = sc[i0], B = sc[i1];
    int stA = A.x + c, enA = A.x + A.y;
    int stB = B.x + c, enB = B.x + B.y;
    float sxA[8], syA[8], sxB[8], syB[8];
#pragma unroll
    for (int k = 0; k < 8; ++k) { sxA[k] = 0.f; syA[k] = 0.f; sxB[k] = 0.f; syB[k] = 0.f; }
    {
        int aA[8], aB[8];
#pragma unroll
        for (int k = 0; k < 8; ++k) {
            int eA = stA + 8 * k;
            int eB = stB + 8 * k;
            aA[k] = __builtin_nontemporal_load(esrc + (eA < enA ? eA : A.x));
            aB[k] = __builtin_nontemporal_load(esrc + (eB < enB ? eB : B.x));
        }
#pragma unroll
        for (int k = 0; k < 8; ++k) {
            bool okA = (stA + 8 * k) < enA;
            bool okB = (stB + 8 * k) < enB;
            float2 fA = __half22float2(hsc2[(okA ? aA[k] : 0) * 8 + j2]);
            float2 fB = __half22float2(hsc2[(okB ? aB[k] : 0) * 8 + j2]);
            sxA[k] += okA ? fA.x : 0.f;  syA[k] += okA ? fA.y : 0.f;
            sxB[k] += okB ? fB.x : 0.f;  syB[k] += okB ? fB.y : 0.f;
        }
    }
    for (int e = stA + 64; e < enA; e += 64) {
        int a[8];
#pragma unroll
        for (int k = 0; k < 8; ++k) {
            int ee = e + 8 * k;
            a[k] = __builtin_nontemporal_load(esrc + (ee < enA ? ee : e));
        }
#pragma unroll
        for (int k = 0; k < 8; ++k) {
            float2 f = __half22float2(hsc2[a[k] * 8 + j2]);
            bool ok = (e + 8 * k) < enA;
            sxA[k] += ok ? f.x : 0.f;
            syA[k] += ok ? f.y : 0.f;
        }
    }
    for (int e = stB + 64; e < enB; e += 64) {
        int a[8];
#pragma unroll
        for (int k = 0; k < 8; ++k) {
            int ee = e + 8 * k;
            a[k] = __builtin_nontemporal_load(esrc + (ee < enB ? ee : e));
        }
#pragma unroll
        for (int k = 0; k < 8; ++k) {
            float2 f = __half22float2(hsc2[a[k] * 8 + j2]);
            bool ok = (e + 8 * k) < enB;
            sxB[k] += ok ? f.x : 0.f;
            syB[k] += ok ? f.y : 0.f;
        }
    }
    float sumxA = ((sxA[0] + sxA[1]) + (sxA[2] + sxA[3])) + ((sxA[4] + sxA[5]) + (sxA[6] + sxA[7]));
    float sumyA = ((syA[0] + syA[1]) + (syA[2] + syA[3])) + ((syA[4] + syA[5]) + (syA[6] + syA[7]));
    float sumxB = ((sxB[0] + sxB[1]) + (sxB[2] + sxB[3])) + ((sxB[4] + sxB[5]) + (sxB[6] + sxB[7]));
    float sumyB = ((syB[0] + syB[1]) + (syB[2] + syB[3])) + ((syB[4] + syB[5]) + (syB[6] + syB[7]));
    sumxA += __shfl_xor(sumxA, 8);  sumyA += __shfl_xor(sumyA, 8);
    sumxA += __shfl_xor(sumxA, 16); sumyA += __shfl_xor(sumyA, 16);
    sumxA += __shfl_xor(sumxA, 32); sumyA += __shfl_xor(sumyA, 32);
    sumxB += __shfl_xor(sumxB, 8);  sumyB += __shfl_xor(sumyB, 8);
    sumxB += __shfl_xor(sumxB, 16); sumyB += __shfl_xor(sumyB, 16);
    sumxB += __shfl_xor(sumxB, 32); sumyB += __shfl_xor(sumyB, 32);
    {   // self-loop terms
        float2 sA = __half22float2(hsc2[i0 * 8 + j2]);
        float2 sB = __half22float2(hsc2[i1 * 8 + j2]);
        sumxA += sA.x;  sumyA += sA.y;
        sumxB += sB.x;  sumyB += sB.y;
    }
    int jo = lane & 31;
    float accA = 0.f, accB = 0.f;
#pragma unroll
    for (int p = 0; p < 8; ++p) {
        float wx = w2s[(2 * p) * NCLS + jo];
        float wy = w2s[(2 * p + 1) * NCLS + jo];
        accA += __shfl(sumxA, p) * wx + __shfl(sumyA, p) * wy;
        accB += __shfl(sumxB, p) * wx + __shfl(sumyB, p) * wy;
    }
    if (lane < 32) {
        out[i0 * NCLS + jo] = b2s[jo] + dinv[i0] * accA;
        out[i1 * NCLS + jo] = b2s[jo] + dinv[i1] * accB;
    }
}

extern "C" void kernel_launch(void* const* d_in, const int* in_sizes, int n_in,
                              void* d_out, int out_size, void* d_ws, size_t ws_size,
                              hipStream_t stream) {
    const float* x  = (const float*)d_in[0];
    const int* ei   = (const int*)d_in[1];      // [2][NE]
    const float* W1 = (const float*)d_in[2];
    const float* b1 = (const float*)d_in[3];
    const float* W2 = (const float*)d_in[4];
    const float* b2 = (const float*)d_in[5];

    const int* src = ei;
    const int* dst = ei + NE;

    int* wsi = (int*)d_ws;
    int*      bcnt  = wsi + OFF_BCNT;
    int2*     sc    = (int2*)(wsi + OFF_SC);
    float*    dinv  = (float*)(wsi + OFF_DINV);
    unsigned* ep    = (unsigned*)(wsi + OFF_EP);   // packed, then esrc
    __half*   xws   = (__half*)(wsi + OFF_XWS);
    __half2*  xws2  = (__half2*)(wsi + OFF_XWS);
    __half2*  hsc2  = (__half2*)(wsi + OFF_HSC);

    float* outp = (float*)d_out;           // [NN*32]
    float* hout = outp + NN * NCLS;        // [NN*16]

    const int B = 256;

    hipMemsetAsync(bcnt, 0, NBP * sizeof(int), stream);
    hipLaunchKernelGGL(k_binA,  dim3((NE + 4095) / 4096), dim3(512), 0, stream, src, dst, bcnt, ep);
    hipLaunchKernelGGL(k_binB,  dim3(NB), dim3(B), 0, stream, ep, bcnt, sc, dinv);
    hipLaunchKernelGGL(k_xw,    dim3((NN + 127) / 128), dim3(B), 0, stream, x, W1, dinv, xws);
    hipLaunchKernelGGL(k_gather1, dim3((NHALF * 64 + B - 1) / B), dim3(B), 0, stream,
                       sc, (const int*)ep, xws2, dinv, b1, hout, hsc2);
    hipLaunchKernelGGL(k_gather2h, dim3((NHALF * 64 + B - 1) / B), dim3(B), 0, stream,
                       sc, (const int*)ep, hsc2, dinv, W2, b2, outp);
}

// Round 18
// 167.911 us; speedup vs baseline: 1.5802x; 1.0707x over previous
//
#include <hip/hip_runtime.h>
#include <hip/hip_fp16.h>

// GCN 2-layer forward, CSR-gather with fixed-capacity radix binning.
// (R17 base — 179.8 us — with resized binning kernels.)
//   (memset) : zero bucket counters
//   k_binA   : 1024 thr x 8192 edges, 391 blocks all-co-resident;
//              halved global-atomic reservation chains
//   k_binB   : 512 thr per bucket; halved record-pass iterations
//   k_xw     : xws = f16((x @ W1) * dinv)  [f32 W1 LDS, XOR-swizzled float4]
//   k_gather1 : 2 nodes/wave, half2, 8-way edge split, peeled round-0
//   k_gather2h: same over hsc; fused W2 epilogue (both nodes)
// d_out = [out (N*32) | h (N*16)]

#define NN 100000
#define NHALF 50000
#define NE 3200000
#define FIN 512
#define HID 16
#define NCLS 32
#define NB 391          // ceil(NN/256)
#define NBP 512         // padded bucket slots
#define CAP_B 9216      // fixed slots per bucket (mean 8184, +11 sigma)

// workspace element offsets (4-byte units)
#define OFF_BCNT  0                     // int [NBP]
#define OFF_SC    (NBP)                 // int2 [NN]  (start, cnt)
#define OFF_DINV  (NBP + 2*NN)          // float [NN]
#define OFF_EP    (NBP + 3*NN)          // u32 [NB*CAP_B]; becomes esrc
#define OFF_XWS   (OFF_EP + NB*CAP_B)   // half [NN*16] = NN*8 words
#define OFF_HSC   (OFF_XWS + NN*8)      // half [NN*16] = NN*8 words

// Bin edges into fixed-cap bucket regions. 1024 thr/block, 8 edges/thread,
// 8192 edges/block, 391 blocks (all co-resident: 2 blocks/CU capacity).
__global__ __launch_bounds__(1024) void k_binA(const int* __restrict__ src,
                                               const int* __restrict__ dst,
                                               int* __restrict__ bcnt,
                                               unsigned* __restrict__ ep) {
    __shared__ int hist[NBP];
    __shared__ int gpos[NBP];
    int tid = threadIdx.x;
    if (tid < NBP) hist[tid] = 0;
    __syncthreads();
    int base = blockIdx.x * 8192;
    unsigned rec[8];
    int meta[8];                        // (p_local << 9) | bucket, or -1
#pragma unroll
    for (int k = 0; k < 8; ++k) {
        int e = base + tid + k * 1024;
        if (e < NE) {
            int s = __builtin_nontemporal_load(src + e);
            int d = __builtin_nontemporal_load(dst + e);
            int b = d >> 8;
            int p = atomicAdd(&hist[b], 1);
            rec[k] = ((unsigned)s << 8) | (unsigned)(d & 255);
            meta[k] = (p << 9) | b;
        } else meta[k] = -1;
    }
    __syncthreads();
    if (tid < NBP) {
        int v = hist[tid];
        if (v > 0) gpos[tid] = atomicAdd(&bcnt[tid], v);   // direct reservation
    }
    __syncthreads();
#pragma unroll
    for (int k = 0; k < 8; ++k) {
        if (meta[k] >= 0) {
            int b = meta[k] & 511;
            int p = meta[k] >> 9;
            ep[b * CAP_B + gpos[b] + p] = rec[k];   // plain store: L2 absorbs
        }
    }
}

// Per-bucket CSR build in LDS. Block b owns nodes [b*256, b*256+256).
// 512 threads: halved record-pass iterations; scan guarded to tid<256.
__global__ __launch_bounds__(512) void k_binB(unsigned* __restrict__ ep,
                                              const int* __restrict__ bcnt,
                                              int2* __restrict__ sc,
                                              float* __restrict__ dinv) {
    __shared__ int nh[256];
    __shared__ int ns[256];
    __shared__ int np_[256];
    __shared__ int esL[CAP_B];
    int tid = threadIdx.x;
    int b = blockIdx.x;
    int gbase = b * CAP_B;
    int bc = bcnt[b];
    if (bc > CAP_B) bc = CAP_B;         // defensive clamp
    if (tid < 256) nh[tid] = 0;
    __syncthreads();
    for (int t = tid; t < bc; t += 512)
        atomicAdd(&nh[ep[gbase + t] & 255], 1);
    __syncthreads();
    int v = 0;
    if (tid < 256) { v = nh[tid]; ns[tid] = v; }
    __syncthreads();
#pragma unroll
    for (int o = 1; o < 256; o <<= 1) {
        int u = (tid >= o && tid < 256) ? ns[tid - o] : 0;
        __syncthreads();
        if (tid < 256) ns[tid] += u;
        __syncthreads();
    }
    int ex = 0;
    if (tid < 256) {
        ex = ns[tid] - v;               // exclusive start within bucket
        np_[tid] = ex;
    }
    __syncthreads();
    for (int t = tid; t < bc; t += 512) {
        unsigned r = ep[gbase + t];
        int dl = r & 255;
        int p = atomicAdd(&np_[dl], 1);
        esL[p] = (int)(r >> 8);
    }
    __syncthreads();
    for (int t = tid; t < bc; t += 512)
        ep[gbase + t] = (unsigned)esL[t];   // in-place: ep becomes esrc
    if (tid < 256) {
        int node = b * 256 + tid;
        if (node < NN) {
            sc[node] = make_int2(gbase + ex, v);
            dinv[node] = rsqrtf((float)(v + 1));
        }
    }
}

// GEMM1: 4-way k-split, 2 nodes per thread; XOR-swizzled f32 W1 in LDS;
// f16 output. (R7-proven structure.)
__global__ __launch_bounds__(256) void k_xw(const float* __restrict__ x,
                                            const float* __restrict__ W1,
                                            const float* __restrict__ dinv,
                                            __half* __restrict__ xws) {
    __shared__ float w1[FIN * HID];     // 32 KB, XOR-swizzled float4 blocks
    for (int t = threadIdx.x; t < FIN * HID; t += 256) {
        int k = t >> 4, j = t & 15;
        int s = (k * 4 + ((j >> 2) ^ ((k >> 2) & 3))) * 4 + (j & 3);
        w1[s] = W1[t];
    }
    __syncthreads();
    int w  = threadIdx.x >> 6;          // wave in block (0..3)
    int nl = (threadIdx.x >> 2) & 15;   // node slot
    int c  = threadIdx.x & 3;           // k-split group
    int n0 = blockIdx.x * 128 + w * 32 + nl;
    int n1 = n0 + 16;
    bool v0 = n0 < NN, v1 = n1 < NN;
    const float4* x4 = reinterpret_cast<const float4*>(x);
    const float4* r0 = x4 + (v0 ? (size_t)n0 * (FIN / 4) : 0);
    const float4* r1 = x4 + (v1 ? (size_t)n1 * (FIN / 4) : 0);
    const float4* wv = reinterpret_cast<const float4*>(w1);
    float a0[HID], a1[HID];
#pragma unroll
    for (int j = 0; j < HID; ++j) { a0[j] = 0.f; a1[j] = 0.f; }
#pragma unroll 4
    for (int t = 0; t < 32; ++t) {
        int qk = c + 4 * t;             // float4-quad index into the row
        float4 xv0 = r0[qk];
        float4 xv1 = r1[qk];
        const float4* wb = wv + qk * 16;
#pragma unroll
        for (int e = 0; e < 4; ++e) {
            float xe0 = (e == 0) ? xv0.x : (e == 1) ? xv0.y : (e == 2) ? xv0.z : xv0.w;
            float xe1 = (e == 0) ? xv1.x : (e == 1) ? xv1.y : (e == 2) ? xv1.z : xv1.w;
#pragma unroll
            for (int j4 = 0; j4 < 4; ++j4) {
                float4 w4 = wb[e * 4 + (j4 ^ c)];   // true w1[k][j4*4..+3]
                a0[j4 * 4 + 0] += xe0 * w4.x;
                a0[j4 * 4 + 1] += xe0 * w4.y;
                a0[j4 * 4 + 2] += xe0 * w4.z;
                a0[j4 * 4 + 3] += xe0 * w4.w;
                a1[j4 * 4 + 0] += xe1 * w4.x;
                a1[j4 * 4 + 1] += xe1 * w4.y;
                a1[j4 * 4 + 2] += xe1 * w4.z;
                a1[j4 * 4 + 3] += xe1 * w4.w;
            }
        }
    }
#pragma unroll
    for (int j = 0; j < HID; ++j) {
        a0[j] += __shfl_xor(a0[j], 1);
        a0[j] += __shfl_xor(a0[j], 2);
        a1[j] += __shfl_xor(a1[j], 1);
        a1[j] += __shfl_xor(a1[j], 2);
    }
    if (c == 0) {
        if (v0) {
            float dv = dinv[n0];
            __half2 hv[8];
#pragma unroll
            for (int k = 0; k < 8; ++k)
                hv[k] = __floats2half2_rn(a0[2 * k] * dv, a0[2 * k + 1] * dv);
            float4* o = reinterpret_cast<float4*>(xws + (size_t)n0 * HID);
            o[0] = *reinterpret_cast<float4*>(&hv[0]);
            o[1] = *reinterpret_cast<float4*>(&hv[4]);
        }
        if (v1) {
            float dv = dinv[n1];
            __half2 hv[8];
#pragma unroll
            for (int k = 0; k < 8; ++k)
                hv[k] = __floats2half2_rn(a1[2 * k] * dv, a1[2 * k + 1] * dv);
            float4* o = reinterpret_cast<float4*>(xws + (size_t)n1 * HID);
            o[0] = *reinterpret_cast<float4*>(&hv[0]);
            o[1] = *reinterpret_cast<float4*>(&hv[4]);
        }
    }
}

// Gather layer 1: 2 nodes per wave (i, i+NHALF). j2 = lane&7, c = lane>>3.
// Peeled round-0 issues both nodes' sc/idx/gather chains in parallel.
__global__ __launch_bounds__(256) void k_gather1(const int2* __restrict__ sc,
                                                 const int* __restrict__ esrc,
                                                 const __half2* __restrict__ xws2,
                                                 const float* __restrict__ dinv,
                                                 const float* __restrict__ b1,
                                                 float* __restrict__ hout,
                                                 __half2* __restrict__ hsc2) {
    int wv = (blockIdx.x * 256 + threadIdx.x) >> 6;
    if (wv >= NHALF) return;
    int i0 = wv, i1 = wv + NHALF;
    int lane = threadIdx.x & 63;
    int j2 = lane & 7;
    int c = lane >> 3;                  // 0..7
    int2 A = sc[i0], B = sc[i1];
    int stA = A.x + c, enA = A.x + A.y;
    int stB = B.x + c, enB = B.x + B.y;
    float sxA[8], syA[8], sxB[8], syB[8];
#pragma unroll
    for (int k = 0; k < 8; ++k) { sxA[k] = 0.f; syA[k] = 0.f; sxB[k] = 0.f; syB[k] = 0.f; }
    // round 0: both nodes, 64 edges each in flight
    {
        int aA[8], aB[8];
#pragma unroll
        for (int k = 0; k < 8; ++k) {
            int eA = stA + 8 * k;
            int eB = stB + 8 * k;
            aA[k] = __builtin_nontemporal_load(esrc + (eA < enA ? eA : A.x));
            aB[k] = __builtin_nontemporal_load(esrc + (eB < enB ? eB : B.x));
        }
#pragma unroll
        for (int k = 0; k < 8; ++k) {
            bool okA = (stA + 8 * k) < enA;
            bool okB = (stB + 8 * k) < enB;
            float2 fA = __half22float2(xws2[(okA ? aA[k] : 0) * 8 + j2]);
            float2 fB = __half22float2(xws2[(okB ? aB[k] : 0) * 8 + j2]);
            sxA[k] += okA ? fA.x : 0.f;  syA[k] += okA ? fA.y : 0.f;
            sxB[k] += okB ? fB.x : 0.f;  syB[k] += okB ? fB.y : 0.f;
        }
    }
    // remainders (rare: deg > 64)
    for (int e = stA + 64; e < enA; e += 64) {
        int a[8];
#pragma unroll
        for (int k = 0; k < 8; ++k) {
            int ee = e + 8 * k;
            a[k] = __builtin_nontemporal_load(esrc + (ee < enA ? ee : e));
        }
#pragma unroll
        for (int k = 0; k < 8; ++k) {
            float2 f = __half22float2(xws2[a[k] * 8 + j2]);
            bool ok = (e + 8 * k) < enA;
            sxA[k] += ok ? f.x : 0.f;
            syA[k] += ok ? f.y : 0.f;
        }
    }
    for (int e = stB + 64; e < enB; e += 64) {
        int a[8];
#pragma unroll
        for (int k = 0; k < 8; ++k) {
            int ee = e + 8 * k;
            a[k] = __builtin_nontemporal_load(esrc + (ee < enB ? ee : e));
        }
#pragma unroll
        for (int k = 0; k < 8; ++k) {
            float2 f = __half22float2(xws2[a[k] * 8 + j2]);
            bool ok = (e + 8 * k) < enB;
            sxB[k] += ok ? f.x : 0.f;
            syB[k] += ok ? f.y : 0.f;
        }
    }
    float sumxA = ((sxA[0] + sxA[1]) + (sxA[2] + sxA[3])) + ((sxA[4] + sxA[5]) + (sxA[6] + sxA[7]));
    float sumyA = ((syA[0] + syA[1]) + (syA[2] + syA[3])) + ((syA[4] + syA[5]) + (syA[6] + syA[7]));
    float sumxB = ((sxB[0] + sxB[1]) + (sxB[2] + sxB[3])) + ((sxB[4] + sxB[5]) + (sxB[6] + sxB[7]));
    float sumyB = ((syB[0] + syB[1]) + (syB[2] + syB[3])) + ((syB[4] + syB[5]) + (syB[6] + syB[7]));
    sumxA += __shfl_xor(sumxA, 8);  sumyA += __shfl_xor(sumyA, 8);
    sumxA += __shfl_xor(sumxA, 16); sumyA += __shfl_xor(sumyA, 16);
    sumxA += __shfl_xor(sumxA, 32); sumyA += __shfl_xor(sumyA, 32);
    sumxB += __shfl_xor(sumxB, 8);  sumyB += __shfl_xor(sumyB, 8);
    sumxB += __shfl_xor(sumxB, 16); sumyB += __shfl_xor(sumyB, 16);
    sumxB += __shfl_xor(sumxB, 32); sumyB += __shfl_xor(sumyB, 32);
    if (c == 0) {
        float dvA = dinv[i0], dvB = dinv[i1];
        float2 selfA = __half22float2(xws2[i0 * 8 + j2]);
        float2 selfB = __half22float2(xws2[i1 * 8 + j2]);
        float vxA = b1[2 * j2]     + dvA * (sumxA + selfA.x);
        float vyA = b1[2 * j2 + 1] + dvA * (sumyA + selfA.y);
        float vxB = b1[2 * j2]     + dvB * (sumxB + selfB.x);
        float vyB = b1[2 * j2 + 1] + dvB * (sumyB + selfB.y);
        float hxA = vxA > 0.f ? vxA : 0.f, hyA = vyA > 0.f ? vyA : 0.f;
        float hxB = vxB > 0.f ? vxB : 0.f, hyB = vyB > 0.f ? vyB : 0.f;
        *reinterpret_cast<float2*>(hout + i0 * HID + 2 * j2) = make_float2(hxA, hyA);
        *reinterpret_cast<float2*>(hout + i1 * HID + 2 * j2) = make_float2(hxB, hyB);
        hsc2[i0 * 8 + j2] = __floats2half2_rn(hxA * dvA, hyA * dvA);
        hsc2[i1 * 8 + j2] = __floats2half2_rn(hxB * dvB, hyB * dvB);
    }
}

// Gather layer 2 with fused W2: 2 nodes per wave over hsc.
__global__ __launch_bounds__(256) void k_gather2h(const int2* __restrict__ sc,
                                                  const int* __restrict__ esrc,
                                                  const __half2* __restrict__ hsc2,
                                                  const float* __restrict__ dinv,
                                                  const float* __restrict__ W2,
                                                  const float* __restrict__ b2,
                                                  float* __restrict__ out) {
    __shared__ float w2s[HID * NCLS];
    __shared__ float b2s[NCLS];
    for (int t = threadIdx.x; t < HID * NCLS; t += 256) w2s[t] = W2[t];
    if (threadIdx.x < NCLS) b2s[threadIdx.x] = b2[threadIdx.x];
    __syncthreads();
    int wv = (blockIdx.x * 256 + threadIdx.x) >> 6;
    if (wv >= NHALF) return;
    int i0 = wv, i1 = wv + NHALF;
    int lane = threadIdx.x & 63;
    int j2 = lane & 7;
    int c = lane >> 3;                  // 0..7
    int2 A = sc[i0], B = sc[i1];
    int stA = A.x + c, enA = A.x + A.y;
    int stB = B.x + c, enB = B.x + B.y;
    float sxA[8], syA[8], sxB[8], syB[8];
#pragma unroll
    for (int k = 0; k < 8; ++k) { sxA[k] = 0.f; syA[k] = 0.f; sxB[k] = 0.f; syB[k] = 0.f; }
    {
        int aA[8], aB[8];
#pragma unroll
        for (int k = 0; k < 8; ++k) {
            int eA = stA + 8 * k;
            int eB = stB + 8 * k;
            aA[k] = __builtin_nontemporal_load(esrc + (eA < enA ? eA : A.x));
            aB[k] = __builtin_nontemporal_load(esrc + (eB < enB ? eB : B.x));
        }
#pragma unroll
        for (int k = 0; k < 8; ++k) {
            bool okA = (stA + 8 * k) < enA;
            bool okB = (stB + 8 * k) < enB;
            float2 fA = __half22float2(hsc2[(okA ? aA[k] : 0) * 8 + j2]);
            float2 fB = __half22float2(hsc2[(okB ? aB[k] : 0) * 8 + j2]);
            sxA[k] += okA ? fA.x : 0.f;  syA[k] += okA ? fA.y : 0.f;
            sxB[k] += okB ? fB.x : 0.f;  syB[k] += okB ? fB.y : 0.f;
        }
    }
    for (int e = stA + 64; e < enA; e += 64) {
        int a[8];
#pragma unroll
        for (int k = 0; k < 8; ++k) {
            int ee = e + 8 * k;
            a[k] = __builtin_nontemporal_load(esrc + (ee < enA ? ee : e));
        }
#pragma unroll
        for (int k = 0; k < 8; ++k) {
            float2 f = __half22float2(hsc2[a[k] * 8 + j2]);
            bool ok = (e + 8 * k) < enA;
            sxA[k] += ok ? f.x : 0.f;
            syA[k] += ok ? f.y : 0.f;
        }
    }
    for (int e = stB + 64; e < enB; e += 64) {
        int a[8];
#pragma unroll
        for (int k = 0; k < 8; ++k) {
            int ee = e + 8 * k;
            a[k] = __builtin_nontemporal_load(esrc + (ee < enB ? ee : e));
        }
#pragma unroll
        for (int k = 0; k < 8; ++k) {
            float2 f = __half22float2(hsc2[a[k] * 8 + j2]);
            bool ok = (e + 8 * k) < enB;
            sxB[k] += ok ? f.x : 0.f;
            syB[k] += ok ? f.y : 0.f;
        }
    }
    float sumxA = ((sxA[0] + sxA[1]) + (sxA[2] + sxA[3])) + ((sxA[4] + sxA[5]) + (sxA[6] + sxA[7]));
    float sumyA = ((syA[0] + syA[1]) + (syA[2] + syA[3])) + ((syA[4] + syA[5]) + (syA[6] + syA[7]));
    float sumxB = ((sxB[0] + sxB[1]) + (sxB[2] + sxB[3])) + ((sxB[4] + sxB[5]) + (sxB[6] + sxB[7]));
    float sumyB = ((syB[0] + syB[1]) + (syB[2] + syB[3])) + ((syB[4] + syB[5]) + (syB[6] + syB[7]));
    sumxA += __shfl_xor(sumxA, 8);  sumyA += __shfl_xor(sumyA, 8);
    sumxA += __shfl_xor(sumxA, 16); sumyA += __shfl_xor(sumyA, 16);
    sumxA += __shfl_xor(sumxA, 32); sumyA += __shfl_xor(sumyA, 32);
    sumxB += __shfl_xor(sumxB, 8);  sumyB += __shfl_xor(sumyB, 8);
    sumxB += __shfl_xor(sumxB, 16); sumyB += __shfl_xor(sumyB, 16);
    sumxB += __shfl_xor(sumxB, 32); sumyB += __shfl_xor(sumyB, 32);
    {   // self-loop terms
        float2 sA = __half22float2(hsc2[i0 * 8 + j2]);
        float2 sB = __half22float2(hsc2[i1 * 8 + j2]);
        sumxA += sA.x;  sumyA += sA.y;
        sumxB += sB.x;  sumyB += sB.y;
    }
    int jo = lane & 31;
    float accA = 0.f, accB = 0.f;
#pragma unroll
    for (int p = 0; p < 8; ++p) {
        float wx = w2s[(2 * p) * NCLS + jo];
        float wy = w2s[(2 * p + 1) * NCLS + jo];
        accA += __shfl(sumxA, p) * wx + __shfl(sumyA, p) * wy;
        accB += __shfl(sumxB, p) * wx + __shfl(sumyB, p) * wy;
    }
    if (lane < 32) {
        out[i0 * NCLS + jo] = b2s[jo] + dinv[i0] * accA;
        out[i1 * NCLS + jo] = b2s[jo] + dinv[i1] * accB;
    }
}

extern "C" void kernel_launch(void* const* d_in, const int* in_sizes, int n_in,
                              void* d_out, int out_size, void* d_ws, size_t ws_size,
                              hipStream_t stream) {
    const float* x  = (const float*)d_in[0];
    const int* ei   = (const int*)d_in[1];      // [2][NE]
    const float* W1 = (const float*)d_in[2];
    const float* b1 = (const float*)d_in[3];
    const float* W2 = (const float*)d_in[4];
    const float* b2 = (const float*)d_in[5];

    const int* src = ei;
    const int* dst = ei + NE;

    int* wsi = (int*)d_ws;
    int*      bcnt  = wsi + OFF_BCNT;
    int2*     sc    = (int2*)(wsi + OFF_SC);
    float*    dinv  = (float*)(wsi + OFF_DINV);
    unsigned* ep    = (unsigned*)(wsi + OFF_EP);   // packed, then esrc
    __half*   xws   = (__half*)(wsi + OFF_XWS);
    __half2*  xws2  = (__half2*)(wsi + OFF_XWS);
    __half2*  hsc2  = (__half2*)(wsi + OFF_HSC);

    float* outp = (float*)d_out;           // [NN*32]
    float* hout = outp + NN * NCLS;        // [NN*16]

    const int B = 256;

    hipMemsetAsync(bcnt, 0, NBP * sizeof(int), stream);
    hipLaunchKernelGGL(k_binA,  dim3((NE + 8191) / 8192), dim3(1024), 0, stream, src, dst, bcnt, ep);
    hipLaunchKernelGGL(k_binB,  dim3(NB), dim3(512), 0, stream, ep, bcnt, sc, dinv);
    hipLaunchKernelGGL(k_xw,    dim3((NN + 127) / 128), dim3(B), 0, stream, x, W1, dinv, xws);
    hipLaunchKernelGGL(k_gather1, dim3((NHALF * 64 + B - 1) / B), dim3(B), 0, stream,
                       sc, (const int*)ep, xws2, dinv, b1, hout, hsc2);
    hipLaunchKernelGGL(k_gather2h, dim3((NHALF * 64 + B - 1) / B), dim3(B), 0, stream,
                       sc, (const int*)ep, hsc2, dinv, W2, b2, outp);
}

// Round 19
// 167.422 us; speedup vs baseline: 1.5848x; 1.0029x over previous
//
#include <hip/hip_runtime.h>
#include <hip/hip_fp16.h>

// GCN 2-layer forward, CSR-gather with fixed-capacity radix binning.
// (R18 base — 167.9 us — with 4-node-per-thread k_xw.)
//   (memset) : zero bucket counters
//   k_binA   : 1024 thr x 8192 edges, 391 blocks all-co-resident
//   k_binB   : 512 thr per bucket CSR build
//   k_xw     : xws = f16((x @ W1) * dinv); 4 nodes/thread, 256 nodes/block
//   k_gather1 : 2 nodes/wave, half2, 8-way edge split, peeled round-0
//   k_gather2h: same over hsc; fused W2 epilogue (both nodes)
// d_out = [out (N*32) | h (N*16)]

#define NN 100000
#define NHALF 50000
#define NE 3200000
#define FIN 512
#define HID 16
#define NCLS 32
#define NB 391          // ceil(NN/256)
#define NBP 512         // padded bucket slots
#define CAP_B 9216      // fixed slots per bucket (mean 8184, +11 sigma)

// workspace element offsets (4-byte units)
#define OFF_BCNT  0                     // int [NBP]
#define OFF_SC    (NBP)                 // int2 [NN]  (start, cnt)
#define OFF_DINV  (NBP + 2*NN)          // float [NN]
#define OFF_EP    (NBP + 3*NN)          // u32 [NB*CAP_B]; becomes esrc
#define OFF_XWS   (OFF_EP + NB*CAP_B)   // half [NN*16] = NN*8 words
#define OFF_HSC   (OFF_XWS + NN*8)      // half [NN*16] = NN*8 words

// Bin edges into fixed-cap bucket regions. 1024 thr/block, 8 edges/thread.
__global__ __launch_bounds__(1024) void k_binA(const int* __restrict__ src,
                                               const int* __restrict__ dst,
                                               int* __restrict__ bcnt,
                                               unsigned* __restrict__ ep) {
    __shared__ int hist[NBP];
    __shared__ int gpos[NBP];
    int tid = threadIdx.x;
    if (tid < NBP) hist[tid] = 0;
    __syncthreads();
    int base = blockIdx.x * 8192;
    unsigned rec[8];
    int meta[8];                        // (p_local << 9) | bucket, or -1
#pragma unroll
    for (int k = 0; k < 8; ++k) {
        int e = base + tid + k * 1024;
        if (e < NE) {
            int s = __builtin_nontemporal_load(src + e);
            int d = __builtin_nontemporal_load(dst + e);
            int b = d >> 8;
            int p = atomicAdd(&hist[b], 1);
            rec[k] = ((unsigned)s << 8) | (unsigned)(d & 255);
            meta[k] = (p << 9) | b;
        } else meta[k] = -1;
    }
    __syncthreads();
    if (tid < NBP) {
        int v = hist[tid];
        if (v > 0) gpos[tid] = atomicAdd(&bcnt[tid], v);   // direct reservation
    }
    __syncthreads();
#pragma unroll
    for (int k = 0; k < 8; ++k) {
        if (meta[k] >= 0) {
            int b = meta[k] & 511;
            int p = meta[k] >> 9;
            ep[b * CAP_B + gpos[b] + p] = rec[k];   // plain store: L2 absorbs
        }
    }
}

// Per-bucket CSR build in LDS. Block b owns nodes [b*256, b*256+256).
__global__ __launch_bounds__(512) void k_binB(unsigned* __restrict__ ep,
                                              const int* __restrict__ bcnt,
                                              int2* __restrict__ sc,
                                              float* __restrict__ dinv) {
    __shared__ int nh[256];
    __shared__ int ns[256];
    __shared__ int np_[256];
    __shared__ int esL[CAP_B];
    int tid = threadIdx.x;
    int b = blockIdx.x;
    int gbase = b * CAP_B;
    int bc = bcnt[b];
    if (bc > CAP_B) bc = CAP_B;         // defensive clamp
    if (tid < 256) nh[tid] = 0;
    __syncthreads();
    for (int t = tid; t < bc; t += 512)
        atomicAdd(&nh[ep[gbase + t] & 255], 1);
    __syncthreads();
    int v = 0;
    if (tid < 256) { v = nh[tid]; ns[tid] = v; }
    __syncthreads();
#pragma unroll
    for (int o = 1; o < 256; o <<= 1) {
        int u = (tid >= o && tid < 256) ? ns[tid - o] : 0;
        __syncthreads();
        if (tid < 256) ns[tid] += u;
        __syncthreads();
    }
    int ex = 0;
    if (tid < 256) {
        ex = ns[tid] - v;               // exclusive start within bucket
        np_[tid] = ex;
    }
    __syncthreads();
    for (int t = tid; t < bc; t += 512) {
        unsigned r = ep[gbase + t];
        int dl = r & 255;
        int p = atomicAdd(&np_[dl], 1);
        esL[p] = (int)(r >> 8);
    }
    __syncthreads();
    for (int t = tid; t < bc; t += 512)
        ep[gbase + t] = (unsigned)esL[t];   // in-place: ep becomes esrc
    if (tid < 256) {
        int node = b * 256 + tid;
        if (node < NN) {
            sc[node] = make_int2(gbase + ex, v);
            dinv[node] = rsqrtf((float)(v + 1));
        }
    }
}

// GEMM1: 4-way k-split, 4 nodes per thread (256 nodes/block, 391 blocks).
// One 32 KB W1 staging serves 256 nodes; each LDS float4 fetch feeds 16 FMAs.
__global__ __launch_bounds__(256) void k_xw(const float* __restrict__ x,
                                            const float* __restrict__ W1,
                                            const float* __restrict__ dinv,
                                            __half* __restrict__ xws) {
    __shared__ float w1[FIN * HID];     // 32 KB, XOR-swizzled float4 blocks
    for (int t = threadIdx.x; t < FIN * HID; t += 256) {
        int k = t >> 4, j = t & 15;
        int s = (k * 4 + ((j >> 2) ^ ((k >> 2) & 3))) * 4 + (j & 3);
        w1[s] = W1[t];
    }
    __syncthreads();
    int w  = threadIdx.x >> 6;          // wave in block (0..3)
    int nl = (threadIdx.x >> 2) & 15;   // node slot
    int c  = threadIdx.x & 3;           // k-split group
    int nb = blockIdx.x * 256 + w * 64 + nl;
    int n0 = nb, n1 = nb + 16, n2 = nb + 32, n3 = nb + 48;
    bool v0 = n0 < NN, v1 = n1 < NN, v2 = n2 < NN, v3 = n3 < NN;
    const float4* x4 = reinterpret_cast<const float4*>(x);
    const float4* r0 = x4 + (v0 ? (size_t)n0 * (FIN / 4) : 0);
    const float4* r1 = x4 + (v1 ? (size_t)n1 * (FIN / 4) : 0);
    const float4* r2 = x4 + (v2 ? (size_t)n2 * (FIN / 4) : 0);
    const float4* r3 = x4 + (v3 ? (size_t)n3 * (FIN / 4) : 0);
    const float4* wv = reinterpret_cast<const float4*>(w1);
    float a0[HID], a1[HID], a2[HID], a3[HID];
#pragma unroll
    for (int j = 0; j < HID; ++j) { a0[j] = 0.f; a1[j] = 0.f; a2[j] = 0.f; a3[j] = 0.f; }
#pragma unroll 2
    for (int t = 0; t < 32; ++t) {
        int qk = c + 4 * t;             // float4-quad index into the row
        float4 xv0 = r0[qk];
        float4 xv1 = r1[qk];
        float4 xv2 = r2[qk];
        float4 xv3 = r3[qk];
        const float4* wb = wv + qk * 16;
#pragma unroll
        for (int e = 0; e < 4; ++e) {
            float xe0 = (e == 0) ? xv0.x : (e == 1) ? xv0.y : (e == 2) ? xv0.z : xv0.w;
            float xe1 = (e == 0) ? xv1.x : (e == 1) ? xv1.y : (e == 2) ? xv1.z : xv1.w;
            float xe2 = (e == 0) ? xv2.x : (e == 1) ? xv2.y : (e == 2) ? xv2.z : xv2.w;
            float xe3 = (e == 0) ? xv3.x : (e == 1) ? xv3.y : (e == 2) ? xv3.z : xv3.w;
#pragma unroll
            for (int j4 = 0; j4 < 4; ++j4) {
                float4 w4 = wb[e * 4 + (j4 ^ c)];   // true w1[k][j4*4..+3]
                a0[j4 * 4 + 0] += xe0 * w4.x;
                a0[j4 * 4 + 1] += xe0 * w4.y;
                a0[j4 * 4 + 2] += xe0 * w4.z;
                a0[j4 * 4 + 3] += xe0 * w4.w;
                a1[j4 * 4 + 0] += xe1 * w4.x;
                a1[j4 * 4 + 1] += xe1 * w4.y;
                a1[j4 * 4 + 2] += xe1 * w4.z;
                a1[j4 * 4 + 3] += xe1 * w4.w;
                a2[j4 * 4 + 0] += xe2 * w4.x;
                a2[j4 * 4 + 1] += xe2 * w4.y;
                a2[j4 * 4 + 2] += xe2 * w4.z;
                a2[j4 * 4 + 3] += xe2 * w4.w;
                a3[j4 * 4 + 0] += xe3 * w4.x;
                a3[j4 * 4 + 1] += xe3 * w4.y;
                a3[j4 * 4 + 2] += xe3 * w4.z;
                a3[j4 * 4 + 3] += xe3 * w4.w;
            }
        }
    }
#pragma unroll
    for (int j = 0; j < HID; ++j) {
        a0[j] += __shfl_xor(a0[j], 1);
        a0[j] += __shfl_xor(a0[j], 2);
        a1[j] += __shfl_xor(a1[j], 1);
        a1[j] += __shfl_xor(a1[j], 2);
        a2[j] += __shfl_xor(a2[j], 1);
        a2[j] += __shfl_xor(a2[j], 2);
        a3[j] += __shfl_xor(a3[j], 1);
        a3[j] += __shfl_xor(a3[j], 2);
    }
    if (c == 0) {
        if (v0) {
            float dv = dinv[n0];
            __half2 hv[8];
#pragma unroll
            for (int k = 0; k < 8; ++k)
                hv[k] = __floats2half2_rn(a0[2 * k] * dv, a0[2 * k + 1] * dv);
            float4* o = reinterpret_cast<float4*>(xws + (size_t)n0 * HID);
            o[0] = *reinterpret_cast<float4*>(&hv[0]);
            o[1] = *reinterpret_cast<float4*>(&hv[4]);
        }
        if (v1) {
            float dv = dinv[n1];
            __half2 hv[8];
#pragma unroll
            for (int k = 0; k < 8; ++k)
                hv[k] = __floats2half2_rn(a1[2 * k] * dv, a1[2 * k + 1] * dv);
            float4* o = reinterpret_cast<float4*>(xws + (size_t)n1 * HID);
            o[0] = *reinterpret_cast<float4*>(&hv[0]);
            o[1] = *reinterpret_cast<float4*>(&hv[4]);
        }
        if (v2) {
            float dv = dinv[n2];
            __half2 hv[8];
#pragma unroll
            for (int k = 0; k < 8; ++k)
                hv[k] = __floats2half2_rn(a2[2 * k] * dv, a2[2 * k + 1] * dv);
            float4* o = reinterpret_cast<float4*>(xws + (size_t)n2 * HID);
            o[0] = *reinterpret_cast<float4*>(&hv[0]);
            o[1] = *reinterpret_cast<float4*>(&hv[4]);
        }
        if (v3) {
            float dv = dinv[n3];
            __half2 hv[8];
#pragma unroll
            for (int k = 0; k < 8; ++k)
                hv[k] = __floats2half2_rn(a3[2 * k] * dv, a3[2 * k + 1] * dv);
            float4* o = reinterpret_cast<float4*>(xws + (size_t)n3 * HID);
            o[0] = *reinterpret_cast<float4*>(&hv[0]);
            o[1] = *reinterpret_cast<float4*>(&hv[4]);
        }
    }
}

// Gather layer 1: 2 nodes per wave (i, i+NHALF). j2 = lane&7, c = lane>>3.
__global__ __launch_bounds__(256) void k_gather1(const int2* __restrict__ sc,
                                                 const int* __restrict__ esrc,
                                                 const __half2* __restrict__ xws2,
                                                 const float* __restrict__ dinv,
                                                 const float* __restrict__ b1,
                                                 float* __restrict__ hout,
                                                 __half2* __restrict__ hsc2) {
    int wv = (blockIdx.x * 256 + threadIdx.x) >> 6;
    if (wv >= NHALF) return;
    int i0 = wv, i1 = wv + NHALF;
    int lane = threadIdx.x & 63;
    int j2 = lane & 7;
    int c = lane >> 3;                  // 0..7
    int2 A = sc[i0], B = sc[i1];
    int stA = A.x + c, enA = A.x + A.y;
    int stB = B.x + c, enB = B.x + B.y;
    float sxA[8], syA[8], sxB[8], syB[8];
#pragma unroll
    for (int k = 0; k < 8; ++k) { sxA[k] = 0.f; syA[k] = 0.f; sxB[k] = 0.f; syB[k] = 0.f; }
    {
        int aA[8], aB[8];
#pragma unroll
        for (int k = 0; k < 8; ++k) {
            int eA = stA + 8 * k;
            int eB = stB + 8 * k;
            aA[k] = __builtin_nontemporal_load(esrc + (eA < enA ? eA : A.x));
            aB[k] = __builtin_nontemporal_load(esrc + (eB < enB ? eB : B.x));
        }
#pragma unroll
        for (int k = 0; k < 8; ++k) {
            bool okA = (stA + 8 * k) < enA;
            bool okB = (stB + 8 * k) < enB;
            float2 fA = __half22float2(xws2[(okA ? aA[k] : 0) * 8 + j2]);
            float2 fB = __half22float2(xws2[(okB ? aB[k] : 0) * 8 + j2]);
            sxA[k] += okA ? fA.x : 0.f;  syA[k] += okA ? fA.y : 0.f;
            sxB[k] += okB ? fB.x : 0.f;  syB[k] += okB ? fB.y : 0.f;
        }
    }
    for (int e = stA + 64; e < enA; e += 64) {
        int a[8];
#pragma unroll
        for (int k = 0; k < 8; ++k) {
            int ee = e + 8 * k;
            a[k] = __builtin_nontemporal_load(esrc + (ee < enA ? ee : e));
        }
#pragma unroll
        for (int k = 0; k < 8; ++k) {
            float2 f = __half22float2(xws2[a[k] * 8 + j2]);
            bool ok = (e + 8 * k) < enA;
            sxA[k] += ok ? f.x : 0.f;
            syA[k] += ok ? f.y : 0.f;
        }
    }
    for (int e = stB + 64; e < enB; e += 64) {
        int a[8];
#pragma unroll
        for (int k = 0; k < 8; ++k) {
            int ee = e + 8 * k;
            a[k] = __builtin_nontemporal_load(esrc + (ee < enB ? ee : e));
        }
#pragma unroll
        for (int k = 0; k < 8; ++k) {
            float2 f = __half22float2(xws2[a[k] * 8 + j2]);
            bool ok = (e + 8 * k) < enB;
            sxB[k] += ok ? f.x : 0.f;
            syB[k] += ok ? f.y : 0.f;
        }
    }
    float sumxA = ((sxA[0] + sxA[1]) + (sxA[2] + sxA[3])) + ((sxA[4] + sxA[5]) + (sxA[6] + sxA[7]));
    float sumyA = ((syA[0] + syA[1]) + (syA[2] + syA[3])) + ((syA[4] + syA[5]) + (syA[6] + syA[7]));
    float sumxB = ((sxB[0] + sxB[1]) + (sxB[2] + sxB[3])) + ((sxB[4] + sxB[5]) + (sxB[6] + sxB[7]));
    float sumyB = ((syB[0] + syB[1]) + (syB[2] + syB[3])) + ((syB[4] + syB[5]) + (syB[6] + syB[7]));
    sumxA += __shfl_xor(sumxA, 8);  sumyA += __shfl_xor(sumyA, 8);
    sumxA += __shfl_xor(sumxA, 16); sumyA += __shfl_xor(sumyA, 16);
    sumxA += __shfl_xor(sumxA, 32); sumyA += __shfl_xor(sumyA, 32);
    sumxB += __shfl_xor(sumxB, 8);  sumyB += __shfl_xor(sumyB, 8);
    sumxB += __shfl_xor(sumxB, 16); sumyB += __shfl_xor(sumyB, 16);
    sumxB += __shfl_xor(sumxB, 32); sumyB += __shfl_xor(sumyB, 32);
    if (c == 0) {
        float dvA = dinv[i0], dvB = dinv[i1];
        float2 selfA = __half22float2(xws2[i0 * 8 + j2]);
        float2 selfB = __half22float2(xws2[i1 * 8 + j2]);
        float vxA = b1[2 * j2]     + dvA * (sumxA + selfA.x);
        float vyA = b1[2 * j2 + 1] + dvA * (sumyA + selfA.y);
        float vxB = b1[2 * j2]     + dvB * (sumxB + selfB.x);
        float vyB = b1[2 * j2 + 1] + dvB * (sumyB + selfB.y);
        float hxA = vxA > 0.f ? vxA : 0.f, hyA = vyA > 0.f ? vyA : 0.f;
        float hxB = vxB > 0.f ? vxB : 0.f, hyB = vyB > 0.f ? vyB : 0.f;
        *reinterpret_cast<float2*>(hout + i0 * HID + 2 * j2) = make_float2(hxA, hyA);
        *reinterpret_cast<float2*>(hout + i1 * HID + 2 * j2) = make_float2(hxB, hyB);
        hsc2[i0 * 8 + j2] = __floats2half2_rn(hxA * dvA, hyA * dvA);
        hsc2[i1 * 8 + j2] = __floats2half2_rn(hxB * dvB, hyB * dvB);
    }
}

// Gather layer 2 with fused W2: 2 nodes per wave over hsc.
__global__ __launch_bounds__(256) void k_gather2h(const int2* __restrict__ sc,
                                                  const int* __restrict__ esrc,
                                                  const __half2* __restrict__ hsc2,
                                                  const float* __restrict__ dinv,
                                                  const float* __restrict__ W2,
                                                  const float* __restrict__ b2,
                                                  float* __restrict__ out) {
    __shared__ float w2s[HID * NCLS];
    __shared__ float b2s[NCLS];
    for (int t = threadIdx.x; t < HID * NCLS; t += 256) w2s[t] = W2[t];
    if (threadIdx.x < NCLS) b2s[threadIdx.x] = b2[threadIdx.x];
    __syncthreads();
    int wv = (blockIdx.x * 256 + threadIdx.x) >> 6;
    if (wv >= NHALF) return;
    int i0 = wv, i1 = wv + NHALF;
    int lane = threadIdx.x & 63;
    int j2 = lane & 7;
    int c = lane >> 3;                  // 0..7
    int2 A = sc[i0], B = sc[i1];
    int stA = A.x + c, enA = A.x + A.y;
    int stB = B.x + c, enB = B.x + B.y;
    float sxA[8], syA[8], sxB[8], syB[8];
#pragma unroll
    for (int k = 0; k < 8; ++k) { sxA[k] = 0.f; syA[k] = 0.f; sxB[k] = 0.f; syB[k] = 0.f; }
    {
        int aA[8], aB[8];
#pragma unroll
        for (int k = 0; k < 8; ++k) {
            int eA = stA + 8 * k;
            int eB = stB + 8 * k;
            aA[k] = __builtin_nontemporal_load(esrc + (eA < enA ? eA : A.x));
            aB[k] = __builtin_nontemporal_load(esrc + (eB < enB ? eB : B.x));
        }
#pragma unroll
        for (int k = 0; k < 8; ++k) {
            bool okA = (stA + 8 * k) < enA;
            bool okB = (stB + 8 * k) < enB;
            float2 fA = __half22float2(hsc2[(okA ? aA[k] : 0) * 8 + j2]);
            float2 fB = __half22float2(hsc2[(okB ? aB[k] : 0) * 8 + j2]);
            sxA[k] += okA ? fA.x : 0.f;  syA[k] += okA ? fA.y : 0.f;
            sxB[k] += okB ? fB.x : 0.f;  syB[k] += okB ? fB.y : 0.f;
        }
    }
    for (int e = stA + 64; e < enA; e += 64) {
        int a[8];
#pragma unroll
        for (int k = 0; k < 8; ++k) {
            int ee = e + 8 * k;
            a[k] = __builtin_nontemporal_load(esrc + (ee < enA ? ee : e));
        }
#pragma unroll
        for (int k = 0; k < 8; ++k) {
            float2 f = __half22float2(hsc2[a[k] * 8 + j2]);
            bool ok = (e + 8 * k) < enA;
            sxA[k] += ok ? f.x : 0.f;
            syA[k] += ok ? f.y : 0.f;
        }
    }
    for (int e = stB + 64; e < enB; e += 64) {
        int a[8];
#pragma unroll
        for (int k = 0; k < 8; ++k) {
            int ee = e + 8 * k;
            a[k] = __builtin_nontemporal_load(esrc + (ee < enB ? ee : e));
        }
#pragma unroll
        for (int k = 0; k < 8; ++k) {
            float2 f = __half22float2(hsc2[a[k] * 8 + j2]);
            bool ok = (e + 8 * k) < enB;
            sxB[k] += ok ? f.x : 0.f;
            syB[k] += ok ? f.y : 0.f;
        }
    }
    float sumxA = ((sxA[0] + sxA[1]) + (sxA[2] + sxA[3])) + ((sxA[4] + sxA[5]) + (sxA[6] + sxA[7]));
    float sumyA = ((syA[0] + syA[1]) + (syA[2] + syA[3])) + ((syA[4] + syA[5]) + (syA[6] + syA[7]));
    float sumxB = ((sxB[0] + sxB[1]) + (sxB[2] + sxB[3])) + ((sxB[4] + sxB[5]) + (sxB[6] + sxB[7]));
    float sumyB = ((syB[0] + syB[1]) + (syB[2] + syB[3])) + ((syB[4] + syB[5]) + (syB[6] + syB[7]));
    sumxA += __shfl_xor(sumxA, 8);  sumyA += __shfl_xor(sumyA, 8);
    sumxA += __shfl_xor(sumxA, 16); sumyA += __shfl_xor(sumyA, 16);
    sumxA += __shfl_xor(sumxA, 32); sumyA += __shfl_xor(sumyA, 32);
    sumxB += __shfl_xor(sumxB, 8);  sumyB += __shfl_xor(sumyB, 8);
    sumxB += __shfl_xor(sumxB, 16); sumyB += __shfl_xor(sumyB, 16);
    sumxB += __shfl_xor(sumxB, 32); sumyB += __shfl_xor(sumyB, 32);
    {   // self-loop terms
        float2 sA = __half22float2(hsc2[i0 * 8 + j2]);
        float2 sB = __half22float2(hsc2[i1 * 8 + j2]);
        sumxA += sA.x;  sumyA += sA.y;
        sumxB += sB.x;  sumyB += sB.y;
    }
    int jo = lane & 31;
    float accA = 0.f, accB = 0.f;
#pragma unroll
    for (int p = 0; p < 8; ++p) {
        float wx = w2s[(2 * p) * NCLS + jo];
        float wy = w2s[(2 * p + 1) * NCLS + jo];
        accA += __shfl(sumxA, p) * wx + __shfl(sumyA, p) * wy;
        accB += __shfl(sumxB, p) * wx + __shfl(sumyB, p) * wy;
    }
    if (lane < 32) {
        out[i0 * NCLS + jo] = b2s[jo] + dinv[i0] * accA;
        out[i1 * NCLS + jo] = b2s[jo] + dinv[i1] * accB;
    }
}

extern "C" void kernel_launch(void* const* d_in, const int* in_sizes, int n_in,
                              void* d_out, int out_size, void* d_ws, size_t ws_size,
                              hipStream_t stream) {
    const float* x  = (const float*)d_in[0];
    const int* ei   = (const int*)d_in[1];      // [2][NE]
    const float* W1 = (const float*)d_in[2];
    const float* b1 = (const float*)d_in[3];
    const float* W2 = (const float*)d_in[4];
    const float* b2 = (const float*)d_in[5];

    const int* src = ei;
    const int* dst = ei + NE;

    int* wsi = (int*)d_ws;
    int*      bcnt  = wsi + OFF_BCNT;
    int2*     sc    = (int2*)(wsi + OFF_SC);
    float*    dinv  = (float*)(wsi + OFF_DINV);
    unsigned* ep    = (unsigned*)(wsi + OFF_EP);   // packed, then esrc
    __half*   xws   = (__half*)(wsi + OFF_XWS);
    __half2*  xws2  = (__half2*)(wsi + OFF_XWS);
    __half2*  hsc2  = (__half2*)(wsi + OFF_HSC);

    float* outp = (float*)d_out;           // [NN*32]
    float* hout = outp + NN * NCLS;        // [NN*16]

    const int B = 256;

    hipMemsetAsync(bcnt, 0, NBP * sizeof(int), stream);
    hipLaunchKernelGGL(k_binA,  dim3((NE + 8191) / 8192), dim3(1024), 0, stream, src, dst, bcnt, ep);
    hipLaunchKernelGGL(k_binB,  dim3(NB), dim3(512), 0, stream, ep, bcnt, sc, dinv);
    hipLaunchKernelGGL(k_xw,    dim3((NN + 255) / 256), dim3(B), 0, stream, x, W1, dinv, xws);
    hipLaunchKernelGGL(k_gather1, dim3((NHALF * 64 + B - 1) / B), dim3(B), 0, stream,
                       sc, (const int*)ep, xws2, dinv, b1, hout, hsc2);
    hipLaunchKernelGGL(k_gather2h, dim3((NHALF * 64 + B - 1) / B), dim3(B), 0, stream,
                       sc, (const int*)ep, hsc2, dinv, W2, b2, outp);
}